// Round 1
// baseline (158.095 us; speedup 1.0000x reference)
//
#include <hip/hip_runtime.h>

// BlockResMLP mixer, fused single kernel.
// 16384 rows x 1024 cols fp32. Two layers of per-block MLP(32->64 ELU ->32)+residual,
// with a 32x32 within-row transpose between layers (gap=1 then gap=32).
// Strategy: bf16 MFMA 16x16x32 (fp32 accum), one WG = 256 thr = 4 waves = 16 rows,
// wave handles 8 blocks per layer. Weights pre-packed to B-fragment order (bf16) in d_ws.

typedef unsigned short u16t;
typedef __bf16 bf16x8 __attribute__((ext_vector_type(8)));
typedef float f32x4 __attribute__((ext_vector_type(4)));

#define TILE_LD 1032   // u16 elements per tile row (1024 + 8 pad; 2064B rows, 16B aligned)
#define HT_LD   20     // u16 elements per hT feature-row (16 + 4 pad; 40B rows, 8B aligned)

__device__ __forceinline__ u16t f2b(float f) {           // fp32 -> bf16 RNE
  union { float f; unsigned u; } v; v.f = f;
  unsigned r = v.u + 0x7FFFu + ((v.u >> 16) & 1u);
  return (u16t)(r >> 16);
}
__device__ __forceinline__ float b2f(u16t h) {
  union { unsigned u; float f; } v; v.u = ((unsigned)h) << 16;
  return v.f;
}

// ---------------- weight pack: fp32 -> bf16 MFMA B-fragment order ----------------
// pW1[L][n][c=0..3][lane][j=0..7]  : W1[n][k=q*8+j][c*16+t]   (32x64 per block)
// pW2[L][n][f=kc*2+c2][lane][j]    : W2[n][kc*32+q*8+j][c2*16+t] (64x32 per block)
__global__ __launch_bounds__(256) void pack_weights(
    const float* __restrict__ W1a, const float* __restrict__ W2a,
    const float* __restrict__ W1b, const float* __restrict__ W2b,
    u16t* __restrict__ pW1, u16t* __restrict__ pW2) {
  int tidg = blockIdx.x * 256 + threadIdx.x;   // 0..32767
  int tensor = tidg >> 14;                     // 0 = W1, 1 = W2
  int r  = tidg & 16383;
  int L  = r >> 13;
  int r2 = r & 8191;
  int n    = r2 >> 8;
  int f    = (r2 >> 6) & 3;
  int lane = r2 & 63;
  int q = lane >> 4, t = lane & 15;

  union { u16t us[8]; uint4 v; } w;
  if (tensor == 0) {
    const float* src = L ? W1b : W1a;
#pragma unroll
    for (int j = 0; j < 8; j++)
      w.us[j] = f2b(src[n * 2048 + (q * 8 + j) * 64 + f * 16 + t]);
    *(uint4*)(pW1 + (size_t)((((L * 32 + n) * 4 + f) * 64 + lane) * 8)) = w.v;
  } else {
    const float* src = L ? W2b : W2a;
    int kc = f >> 1, c2 = f & 1;
#pragma unroll
    for (int j = 0; j < 8; j++)
      w.us[j] = f2b(src[n * 2048 + (kc * 32 + q * 8 + j) * 32 + c2 * 16 + t]);
    *(uint4*)(pW2 + (size_t)((((L * 32 + n) * 4 + f) * 64 + lane) * 8)) = w.v;
  }
}

// ---------------- main fused kernel ----------------
struct Frags {
  bf16x8 w1[4];   // W1 col-chunks c=0..3
  bf16x8 w2[4];   // W2 frags f=kc*2+c2
  float  b1v[4];
  float  b2v[2];
};

__device__ __forceinline__ void load_frags(Frags& F, int L, int n, int lane, int t,
    const u16t* __restrict__ pW1, const u16t* __restrict__ pW2,
    const float* __restrict__ b1, const float* __restrict__ b2) {
  const int base = ((L * 32 + n) * 4) * 512 + lane * 8;
#pragma unroll
  for (int f = 0; f < 4; f++) {
    F.w1[f] = *(const bf16x8*)(pW1 + base + f * 512);
    F.w2[f] = *(const bf16x8*)(pW2 + base + f * 512);
  }
#pragma unroll
  for (int c = 0; c < 4; c++) F.b1v[c] = b1[n * 64 + c * 16 + t];
  F.b2v[0] = b2[n * 32 + t];
  F.b2v[1] = b2[n * 32 + 16 + t];
}

// L=0: write y1 into tile with swizzle psi(col) = col ^ (((col>>8)&3)<<1)  (z-gather friendly)
// L=1: write out into tile with swizzle phi(col) = col ^ (((col>>5)&7)<<3) (coalesced out phase)
template <int L>
__device__ __forceinline__ void compute_layer(
    const bf16x8* afr, u16t* __restrict__ tile, u16t* __restrict__ hT,
    const u16t* __restrict__ pW1, const u16t* __restrict__ pW2,
    const float* __restrict__ b1, const float* __restrict__ b2,
    int wave, int lane, int q, int t, const bf16x8* ifr) {
  const f32x4 zf = {0.f, 0.f, 0.f, 0.f};
  Frags cur, nxt;
  load_frags(cur, L, wave * 8, lane, t, pW1, pW2, b1, b2);
#pragma unroll
  for (int u = 0; u < 8; u++) {
    const int n = wave * 8 + u;
    if (u < 7) load_frags(nxt, L, n + 1, lane, t, pW1, pW2, b1, b2);

    // h_pre = x_blk @ W1  (4 col-chunks of 16)
    f32x4 accH[4];
#pragma unroll
    for (int c = 0; c < 4; c++)
      accH[c] = __builtin_amdgcn_mfma_f32_16x16x32_bf16(afr[u], cur.w1[c], zf, 0, 0, 0);

    // bias + ELU, pack to wave-private transposed hT[feature][row]
#pragma unroll
    for (int c = 0; c < 4; c++) {
      union { u16t us[4]; ushort4 v; } hw;
#pragma unroll
      for (int r = 0; r < 4; r++) {
        float v = accH[c][r] + cur.b1v[c];
        v = v > 0.f ? v : (__expf(v) - 1.f);
        hw.us[r] = f2b(v);
      }
      *(ushort4*)(hT + (c * 16 + t) * HT_LD + 4 * q) = hw.v;   // rows 4q..4q+3
    }

    // regather h as A-layout frags (k = kc*32 + q*8 + j, m = t)
    union { u16t us[8]; bf16x8 v; } a0, a1;
#pragma unroll
    for (int j = 0; j < 8; j++) {
      a0.us[j] = hT[(q * 8 + j) * HT_LD + t];
      a1.us[j] = hT[(32 + q * 8 + j) * HT_LD + t];
    }

    // y = x*I (residual) + h @ W2 + b2 ; write bf16 to tile with layer swizzle
#pragma unroll
    for (int c2 = 0; c2 < 2; c2++) {
      f32x4 acc = __builtin_amdgcn_mfma_f32_16x16x32_bf16(afr[u], ifr[c2], zf, 0, 0, 0);
      acc = __builtin_amdgcn_mfma_f32_16x16x32_bf16(a0.v, cur.w2[c2],     acc, 0, 0, 0);
      acc = __builtin_amdgcn_mfma_f32_16x16x32_bf16(a1.v, cur.w2[2 + c2], acc, 0, 0, 0);
#pragma unroll
      for (int r = 0; r < 4; r++) {
        float v = acc[r] + cur.b2v[c2];
        int row = q * 4 + r;
        int cc  = c2 * 16 + t;
        int phys;
        if (L == 0) phys = n * 32 + (cc ^ ((((n >> 3) & 3)) << 1));       // psi
        else        phys = (cc * 32 + n) ^ ((cc & 7) << 3);               // phi
        tile[row * TILE_LD + phys] = f2b(v);
      }
    }
    cur = nxt;
  }
}

__global__ __launch_bounds__(256) void mixer_kernel(
    const float* __restrict__ x,
    const float* __restrict__ b1a, const float* __restrict__ b2a,
    const float* __restrict__ b1b, const float* __restrict__ b2b,
    const u16t* __restrict__ pW1, const u16t* __restrict__ pW2,
    float* __restrict__ out) {
  __shared__ u16t tile[16 * TILE_LD];     // 33 KB: y1 (psi layout) then out (phi layout)
  __shared__ u16t hT[4][64 * HT_LD];      // 10 KB: wave-private hidden scratch

  const int tid  = threadIdx.x;
  const int wave = tid >> 6, lane = tid & 63;
  const int q = lane >> 4, t = lane & 15;
  const int r0 = blockIdx.x * 16;

  // identity B-frags for the residual MFMA: I[k=q*8+j][cc=c2*16+t]
  bf16x8 ifr[2];
#pragma unroll
  for (int c2 = 0; c2 < 2; c2++) {
    union { u16t us[8]; bf16x8 v; } w;
#pragma unroll
    for (int j = 0; j < 8; j++)
      w.us[j] = ((q * 8 + j) == (c2 * 16 + t)) ? (u16t)0x3F80 : (u16t)0;
    ifr[c2] = w.v;
  }

  // ---- layer 1: A-frags straight from global (block = 128B row segment) ----
  bf16x8 afr[8];
#pragma unroll
  for (int u = 0; u < 8; u++) {
    const int n = wave * 8 + u;
    const float* gp = x + (size_t)(r0 + t) * 1024 + n * 32 + q * 8;
    float4 v0 = *(const float4*)gp;
    float4 v1 = *(const float4*)(gp + 4);
    union { u16t us[8]; bf16x8 v; } a;
    a.us[0] = f2b(v0.x); a.us[1] = f2b(v0.y); a.us[2] = f2b(v0.z); a.us[3] = f2b(v0.w);
    a.us[4] = f2b(v1.x); a.us[5] = f2b(v1.y); a.us[6] = f2b(v1.z); a.us[7] = f2b(v1.w);
    afr[u] = a.v;
  }
  compute_layer<0>(afr, tile, hT[wave], pW1, pW2, b1a, b2a, wave, lane, q, t, ifr);
  __syncthreads();

  // ---- layer 2: gather z[m][k] = y1[m][k*32+n2] from psi-swizzled tile ----
#pragma unroll
  for (int u = 0; u < 8; u++) {
    const int n2 = wave * 8 + u;
    const int nx = n2 ^ (q << 1);          // psi on reader side
    union { u16t us[8]; bf16x8 v; } a;
#pragma unroll
    for (int j = 0; j < 8; j++)
      a.us[j] = tile[t * TILE_LD + (q * 8 + j) * 32 + nx];
    afr[u] = a.v;
  }
  __syncthreads();                          // all gathers done before tile is overwritten
  compute_layer<1>(afr, tile, hT[wave], pW1, pW2, b1b, b2b, wave, lane, q, t, ifr);
  __syncthreads();

  // ---- output: phi-swizzled tile -> coalesced fp32 stores ----
#pragma unroll
  for (int i = 0; i < 16; i++) {
    int e = i * 256 + tid;
    int row = e >> 8, g = e & 255;
    int C = 4 * g;
    int phys = C ^ (((g >> 3) & 7) << 3);   // phi (XOR bits 3..5, 4-el groups intact)
    ushort4 hv = *(const ushort4*)(tile + row * TILE_LD + phys);
    float4 o;
    o.x = b2f(hv.x); o.y = b2f(hv.y); o.z = b2f(hv.z); o.w = b2f(hv.w);
    *(float4*)(out + (size_t)(r0 + row) * 1024 + C) = o;
  }
}

extern "C" void kernel_launch(void* const* d_in, const int* in_sizes, int n_in,
                              void* d_out, int out_size, void* d_ws, size_t ws_size,
                              hipStream_t stream) {
  const float* x   = (const float*)d_in[0];
  const float* W1a = (const float*)d_in[1];
  const float* b1a = (const float*)d_in[2];
  const float* W2a = (const float*)d_in[3];
  const float* b2a = (const float*)d_in[4];
  const float* W1b = (const float*)d_in[5];
  const float* b1b = (const float*)d_in[6];
  const float* W2b = (const float*)d_in[7];
  const float* b2b = (const float*)d_in[8];
  float* out = (float*)d_out;

  u16t* pW1 = (u16t*)d_ws;
  u16t* pW2 = pW1 + 131072;   // 256 KB each, 512 KB total in d_ws

  const int rows = in_sizes[0] / 1024;

  pack_weights<<<128, 256, 0, stream>>>(W1a, W2a, W1b, W2b, pW1, pW2);
  mixer_kernel<<<rows / 16, 256, 0, stream>>>(x, b1a, b2a, b1b, b2b, pW1, pW2, out);
}